// Round 12
// baseline (335.716 us; speedup 1.0000x reference)
//
#include <hip/hip_runtime.h>

typedef float f32x4 __attribute__((ext_vector_type(4)));

#define B 256
#define D 256
#define N 200000
#define C 1000

// ---- K1 block map (grid = 2048, copy first = critical path) ----
#define K1_BLOCKS   2048
#define COPY_BLOCKS 1471   // 0..1470: NT-store bulk copy
#define LOGITS_LO   1471   // 256 blocks
#define NEWROWS_LO  1727   // 256 blocks
#define WIN_BLK     1983   // 1 block: touched + winner resolve + sync-word zero
#define HIST_LO     1984   // 64 blocks: private histograms (no atomics, no zero)
#define HIST_BLOCKS 64

// ---- K2 block map (grid = 2039 <= 2048 co-resident => spins are safe) ----
#define PATCH_LO    1
#define FILL_LO     257
#define FILL_BLOCKS 782            // 782*256 = 200192 >= N
#define CM_LO       (FILL_LO + FILL_BLOCKS)   // 1039
#define K2_BLOCKS   (CM_LO + C)               // 2039

// ---------------- ws layout (bytes) ----------------
#define WS_NEWROWS_OFF  0          // B*D f32 = 262144
#define WS_NW_OFF       262144     // 1 int
#define WS_FLAG_OFF     262148     // 1 int (K2 scan->fill release)
#define WS_DONE_OFF     262152     // 1 int (K2 fill->cm release)
#define WS_OFFS_OFF     262156     // C int
#define WS_FILLPOS_OFF  266156     // C int
#define WS_CNTS_OFF     270156     // C int
#define WS_TOUCHED_OFF  274156     // C int
#define WS_WROW_OFF     278156     // B int
#define WS_WLAB_OFF     279180     // B int
#define WS_WB_OFF       280204     // B int
#define WS_HB_OFF       281228     // 64*C int = 256000
#define WS_ROWLIST_OFF  537228     // N int = 800000 -> total 1,337,228

// K1: NT-store copy (0..1470) || logits (1471..1726) || new_rows (1727..1982)
//     || touched+winners+syncword-zero (1983) || private label hists (1984..2047)
// Copy: cached loads (features stays MALL-resident across replays) + NT stores
// (writes don't evict it). R9-measured warm ~96-100 us; plain-store variants
// hit the ~3.4 TB/s mixed-stream wall (R10/R11).
__global__ __launch_bounds__(256) void k1_kernel(
    const float* __restrict__ inputs, const float* __restrict__ features,
    const float* __restrict__ cluster_mean, const int* __restrict__ indexes,
    const int* __restrict__ labels, const int* __restrict__ targets,
    float* __restrict__ out_logits, float* __restrict__ out_feats,
    float* __restrict__ new_rows, int* __restrict__ hb, int* __restrict__ touched,
    int* __restrict__ nw, int* __restrict__ w_row, int* __restrict__ w_lab,
    int* __restrict__ w_b, int* __restrict__ flag, int* __restrict__ done)
{
    const int blk = blockIdx.x;
    const int t = threadIdx.x;

    if (blk < COPY_BLOCKS) {
        const f32x4* src = (const f32x4*)features;
        f32x4*       dst = (f32x4*)out_feats;
        const int total4 = N * (D / 4);            // 12,800,000
        const int stride = COPY_BLOCKS * 256;      // 376,576
        int i = blk * 256 + t;
        for (; i + 3 * stride < total4; i += 4 * stride) {
            f32x4 v0 = src[i];
            f32x4 v1 = src[i + stride];
            f32x4 v2 = src[i + 2 * stride];
            f32x4 v3 = src[i + 3 * stride];
            __builtin_nontemporal_store(v0, dst + i);
            __builtin_nontemporal_store(v1, dst + i + stride);
            __builtin_nontemporal_store(v2, dst + i + 2 * stride);
            __builtin_nontemporal_store(v3, dst + i + 3 * stride);
        }
        for (; i < total4; i += stride)
            __builtin_nontemporal_store(src[i], dst + i);
    } else if (blk < NEWROWS_LO) {
        // ---- logits[b,:] = inputs[b] @ cluster_mean.T ----
        __shared__ float sbuf[D];
        int b = blk - LOGITS_LO;
        sbuf[t] = inputs[b * D + t];
        __syncthreads();
        const f32x4* cmv = (const f32x4*)cluster_mean;
        for (int c = t; c < C; c += 256) {
            const f32x4* cm = cmv + (size_t)c * 64;
            float a0 = 0.f, a1 = 0.f, a2 = 0.f, a3 = 0.f;
            #pragma unroll 8
            for (int d4 = 0; d4 < 64; ++d4) {
                f32x4 v = cm[d4];
                const float* si = sbuf + d4 * 4;
                a0 += v.x * si[0];
                a1 += v.y * si[1];
                a2 += v.z * si[2];
                a3 += v.w * si[3];
            }
            out_logits[(size_t)b * C + c] = (a0 + a1) + (a2 + a3);
        }
    } else if (blk < WIN_BLK) {
        // ---- new_rows[b] = l2norm(0.5*features[indexes[b]] + 0.5*inputs[b]) ----
        __shared__ float wpart[4];
        __shared__ float stot;
        int b = blk - NEWROWS_LO;
        int r = indexes[b];
        float x = 0.5f * features[(size_t)r * D + t] + 0.5f * inputs[b * D + t];
        float s = x * x;
        #pragma unroll
        for (int off = 32; off > 0; off >>= 1) s += __shfl_down(s, off);
        if ((t & 63) == 0) wpart[t >> 6] = s;
        __syncthreads();
        if (t == 0) stot = (wpart[0] + wpart[1]) + (wpart[2] + wpart[3]);
        __syncthreads();
        new_rows[b * D + t] = x / sqrtf(stot + 1e-12f);
    } else if (blk == WIN_BLK) {
        // ---- zero touched + sync words; mark touched; resolve winners ----
        __shared__ int sidx[B];
        __shared__ int cnt;
        for (int i = t; i < C; i += 256) touched[i] = 0;
        sidx[t] = indexes[t];
        if (t == 0) { cnt = 0; *flag = 0; *done = 0; }
        __syncthreads();
        touched[targets[t]] = 1;
        bool win = true;
        for (int j = t + 1; j < B; ++j)
            if (sidx[j] == sidx[t]) { win = false; break; }
        if (win) {                       // last-write-wins representative
            int p = atomicAdd(&cnt, 1);
            int r = sidx[t];
            w_row[p] = r;
            w_lab[p] = labels[r];
            w_b[p] = t;
        }
        __syncthreads();
        if (t == 0) *nw = cnt;
    } else {
        // ---- private label histogram: block i writes its own hb row ----
        __shared__ int lh[C];
        for (int i = t; i < C; i += 256) lh[i] = 0;
        __syncthreads();
        const int hb_i = blk - HIST_LO;
        const int stride = HIST_BLOCKS * 256;
        for (int i = hb_i * 256 + t; i < N; i += stride)
            atomicAdd(&lh[labels[i]], 1);
        __syncthreads();
        for (int i = t; i < C; i += 256) hb[hb_i * C + i] = lh[i];
    }
}

// K2: scan (blk 0, releases flag) || patch winners (1..256, independent)
//     || fill rowlist (257..1038, acquire flag, release done)
//     || cluster means (1039..2038, touched blocks acquire done).
// All 2039 blocks co-resident (<=2048 at 8 blocks/CU) => spins cannot deadlock.
// Spin reads use atomic RMW (coherence-point access; volatile L2 reads are NOT
// coherent across XCDs on gfx950).
__global__ __launch_bounds__(256, 8) void k2_kernel(
    const float* __restrict__ cluster_mean, const float* __restrict__ features,
    const float* __restrict__ new_rows, const int* __restrict__ labels,
    float* __restrict__ out_feats, float* __restrict__ out_cm,
    const int* __restrict__ hb, int* __restrict__ offs, int* __restrict__ fillpos,
    int* __restrict__ cnts, const int* __restrict__ touched,
    const int* __restrict__ nw, const int* __restrict__ w_row,
    const int* __restrict__ w_lab, const int* __restrict__ w_b,
    int* __restrict__ rowlist, int* __restrict__ flag, int* __restrict__ done)
{
    const int blk = blockIdx.x;
    const int t = threadIdx.x;

    if (blk == 0) {
        // ---- reduce hb -> totals; exclusive scan -> offs/fillpos/cnts ----
        __shared__ int swt[4];
        int base = t * 4;
        int h0 = 0, h1 = 0, h2 = 0, h3 = 0;
        for (int i = 0; i < HIST_BLOCKS; ++i) {
            const int* row = hb + i * C;
            if (base + 0 < C) h0 += row[base + 0];
            if (base + 1 < C) h1 += row[base + 1];
            if (base + 2 < C) h2 += row[base + 2];
            if (base + 3 < C) h3 += row[base + 3];
        }
        int tot = h0 + h1 + h2 + h3;
        int lane = t & 63;
        int scan = tot;
        #pragma unroll
        for (int off = 1; off < 64; off <<= 1) {
            int v = __shfl_up(scan, off);
            if (lane >= off) scan += v;
        }
        if (lane == 63) swt[t >> 6] = scan;
        __syncthreads();
        int wbase = 0;
        for (int i = 0; i < (t >> 6); ++i) wbase += swt[i];
        int excl = wbase + scan - tot;
        if (base + 0 < C) { offs[base + 0] = excl;                fillpos[base + 0] = excl;                cnts[base + 0] = h0; }
        if (base + 1 < C) { offs[base + 1] = excl + h0;           fillpos[base + 1] = excl + h0;           cnts[base + 1] = h1; }
        if (base + 2 < C) { offs[base + 2] = excl + h0 + h1;      fillpos[base + 2] = excl + h0 + h1;      cnts[base + 2] = h2; }
        if (base + 3 < C) { offs[base + 3] = excl + h0 + h1 + h2; fillpos[base + 3] = excl + h0 + h1 + h2; cnts[base + 3] = h3; }
        __threadfence();
        __syncthreads();
        if (t == 0) atomicExch(flag, 1);   // release
    } else if (blk < FILL_LO) {
        // ---- patch winner rows into out_feats (after K1's copy) ----
        int q = blk - PATCH_LO;
        if (q < *nw)
            out_feats[(size_t)w_row[q] * D + t] = new_rows[w_b[q] * D + t];
    } else if (blk < CM_LO) {
        // ---- fill rowlist (needs offs/fillpos from scan) ----
        if (t == 0) {
            while (atomicAdd(flag, 0) == 0) __builtin_amdgcn_s_sleep(8);
        }
        __syncthreads();
        __threadfence();                   // acquire
        int i = (blk - FILL_LO) * 256 + t;
        if (i < N) {
            int lab = labels[i];
            if (touched[lab]) {
                int p = atomicAdd(&fillpos[lab], 1);   // RMW: coherent
                rowlist[p] = i;
            }
        }
        __threadfence();                   // release rowlist writes
        __syncthreads();
        if (t == 0) atomicAdd(done, 1);
    } else {
        // ---- cluster mean: features sum + winner correction ----
        int c = blk - CM_LO;
        if (!touched[c]) {                 // block-uniform; no spin needed
            out_cm[(size_t)c * D + t] = cluster_mean[(size_t)c * D + t];
            return;
        }
        if (t == 0) {
            while (atomicAdd(done, 0) < FILL_BLOCKS) __builtin_amdgcn_s_sleep(8);
        }
        __syncthreads();
        __threadfence();                   // acquire rowlist
        const int cnt = cnts[c];
        const int off = offs[c];
        float a0 = 0.f, a1 = 0.f, a2 = 0.f, a3 = 0.f;
        int j = 0;
        for (; j + 3 < cnt; j += 4) {
            int r0 = rowlist[off + j + 0];
            int r1 = rowlist[off + j + 1];
            int r2 = rowlist[off + j + 2];
            int r3 = rowlist[off + j + 3];
            a0 += features[(size_t)r0 * D + t];
            a1 += features[(size_t)r1 * D + t];
            a2 += features[(size_t)r2 * D + t];
            a3 += features[(size_t)r3 * D + t];
        }
        for (; j < cnt; ++j)
            a0 += features[(size_t)rowlist[off + j] * D + t];
        float acc = (a0 + a1) + (a2 + a3);
        const int nwv = *nw;
        for (int q = 0; q < nwv; ++q) {
            if (w_lab[q] == c)
                acc += new_rows[w_b[q] * D + t] - features[(size_t)w_row[q] * D + t];
        }
        out_cm[(size_t)c * D + t] = acc / fmaxf((float)cnt, 1.0f);
    }
}

extern "C" void kernel_launch(void* const* d_in, const int* in_sizes, int n_in,
                              void* d_out, int out_size, void* d_ws, size_t ws_size,
                              hipStream_t stream) {
    const float* inputs       = (const float*)d_in[0];
    const float* features     = (const float*)d_in[1];
    const float* cluster_mean = (const float*)d_in[2];
    const int*   indexes      = (const int*)d_in[3];
    const int*   labels       = (const int*)d_in[4];
    const int*   targets      = (const int*)d_in[5];

    float* out_logits = (float*)d_out;                      // B*C
    float* out_feats  = out_logits + (size_t)B * C;         // N*D
    float* out_cm     = out_feats + (size_t)N * D;          // C*D

    char* ws = (char*)d_ws;
    float* new_rows = (float*)(ws + WS_NEWROWS_OFF);
    int*   nw       = (int*)(ws + WS_NW_OFF);
    int*   flag     = (int*)(ws + WS_FLAG_OFF);
    int*   done     = (int*)(ws + WS_DONE_OFF);
    int*   offs     = (int*)(ws + WS_OFFS_OFF);
    int*   fillpos  = (int*)(ws + WS_FILLPOS_OFF);
    int*   cnts     = (int*)(ws + WS_CNTS_OFF);
    int*   touched  = (int*)(ws + WS_TOUCHED_OFF);
    int*   w_row    = (int*)(ws + WS_WROW_OFF);
    int*   w_lab    = (int*)(ws + WS_WLAB_OFF);
    int*   w_b      = (int*)(ws + WS_WB_OFF);
    int*   hb       = (int*)(ws + WS_HB_OFF);
    int*   rowlist  = (int*)(ws + WS_ROWLIST_OFF);

    k1_kernel<<<K1_BLOCKS, 256, 0, stream>>>(inputs, features, cluster_mean,
                                             indexes, labels, targets,
                                             out_logits, out_feats, new_rows,
                                             hb, touched, nw, w_row, w_lab, w_b,
                                             flag, done);
    k2_kernel<<<K2_BLOCKS, 256, 0, stream>>>(cluster_mean, features, new_rows,
                                             labels, out_feats, out_cm,
                                             hb, offs, fillpos, cnts, touched,
                                             nw, w_row, w_lab, w_b, rowlist,
                                             flag, done);
}

// Round 13
// 166.101 us; speedup vs baseline: 2.0212x; 2.0212x over previous
//
#include <hip/hip_runtime.h>

typedef float f32x4 __attribute__((ext_vector_type(4)));

#define B 256
#define D 256
#define N 200000
#define C 1000

// ---- K1 block map (grid = 2048, copy first = critical path) ----
#define K1_BLOCKS   2048
#define COPY_BLOCKS 1471   // 0..1470: NT-store bulk copy
#define LOGITS_LO   1471   // 256 blocks
#define NEWROWS_LO  1727   // 256 blocks
#define WIN_BLK     1983   // 1 block: touched + winner resolve
#define HIST_LO     1984   // 64 blocks: private histograms (no atomics, no zero)
#define HIST_BLOCKS 64

// ---------------- ws layout (bytes) ----------------
#define WS_NEWROWS_OFF  0          // B*D f32 = 262144
#define WS_NW_OFF       262144     // 1 int
#define WS_OFFS_OFF     262148     // C int
#define WS_FILLPOS_OFF  266148     // C int
#define WS_CNTS_OFF     270148     // C int
#define WS_TOUCHED_OFF  274148     // C int
#define WS_WROW_OFF     278148     // B int
#define WS_WLAB_OFF     279172     // B int
#define WS_WB_OFF       280196     // B int
#define WS_HB_OFF       281220     // 64*C int = 256000
#define WS_ROWLIST_OFF  537220     // N int = 800000 -> total 1,337,220

// K1: NT-store copy (0..1470) || logits (1471..1726) || new_rows (1727..1982)
//     || touched+winners (1983) || private label hists (1984..2047).
// Copy: cached loads (features stays MALL-resident across graph replays) + NT
// stores (writes don't evict it). Best measured config (R9): timed ~98 us.
// Plain stores evict features -> mixed-stream wall ~3.3 TB/s (R10/R11).
__global__ __launch_bounds__(256) void k1_kernel(
    const float* __restrict__ inputs, const float* __restrict__ features,
    const float* __restrict__ cluster_mean, const int* __restrict__ indexes,
    const int* __restrict__ labels, const int* __restrict__ targets,
    float* __restrict__ out_logits, float* __restrict__ out_feats,
    float* __restrict__ new_rows, int* __restrict__ hb, int* __restrict__ touched,
    int* __restrict__ nw, int* __restrict__ w_row, int* __restrict__ w_lab,
    int* __restrict__ w_b)
{
    const int blk = blockIdx.x;
    const int t = threadIdx.x;

    if (blk < COPY_BLOCKS) {
        const f32x4* src = (const f32x4*)features;
        f32x4*       dst = (f32x4*)out_feats;
        const int total4 = N * (D / 4);            // 12,800,000
        const int stride = COPY_BLOCKS * 256;      // 376,576
        int i = blk * 256 + t;
        for (; i + 3 * stride < total4; i += 4 * stride) {
            f32x4 v0 = src[i];
            f32x4 v1 = src[i + stride];
            f32x4 v2 = src[i + 2 * stride];
            f32x4 v3 = src[i + 3 * stride];
            __builtin_nontemporal_store(v0, dst + i);
            __builtin_nontemporal_store(v1, dst + i + stride);
            __builtin_nontemporal_store(v2, dst + i + 2 * stride);
            __builtin_nontemporal_store(v3, dst + i + 3 * stride);
        }
        for (; i < total4; i += stride)
            __builtin_nontemporal_store(src[i], dst + i);
    } else if (blk < NEWROWS_LO) {
        // ---- logits[b,:] = inputs[b] @ cluster_mean.T ----
        __shared__ float sbuf[D];
        int b = blk - LOGITS_LO;
        sbuf[t] = inputs[b * D + t];
        __syncthreads();
        const f32x4* cmv = (const f32x4*)cluster_mean;
        for (int c = t; c < C; c += 256) {
            const f32x4* cm = cmv + (size_t)c * 64;
            float a0 = 0.f, a1 = 0.f, a2 = 0.f, a3 = 0.f;
            #pragma unroll 8
            for (int d4 = 0; d4 < 64; ++d4) {
                f32x4 v = cm[d4];
                const float* si = sbuf + d4 * 4;
                a0 += v.x * si[0];
                a1 += v.y * si[1];
                a2 += v.z * si[2];
                a3 += v.w * si[3];
            }
            out_logits[(size_t)b * C + c] = (a0 + a1) + (a2 + a3);
        }
    } else if (blk < WIN_BLK) {
        // ---- new_rows[b] = l2norm(0.5*features[indexes[b]] + 0.5*inputs[b]) ----
        __shared__ float wpart[4];
        __shared__ float stot;
        int b = blk - NEWROWS_LO;
        int r = indexes[b];
        float x = 0.5f * features[(size_t)r * D + t] + 0.5f * inputs[b * D + t];
        float s = x * x;
        #pragma unroll
        for (int off = 32; off > 0; off >>= 1) s += __shfl_down(s, off);
        if ((t & 63) == 0) wpart[t >> 6] = s;
        __syncthreads();
        if (t == 0) stot = (wpart[0] + wpart[1]) + (wpart[2] + wpart[3]);
        __syncthreads();
        new_rows[b * D + t] = x / sqrtf(stot + 1e-12f);
    } else if (blk == WIN_BLK) {
        // ---- zero+mark touched; resolve last-write-wins winners ----
        __shared__ int sidx[B];
        __shared__ int cnt;
        for (int i = t; i < C; i += 256) touched[i] = 0;
        sidx[t] = indexes[t];
        if (t == 0) cnt = 0;
        __syncthreads();
        touched[targets[t]] = 1;
        bool win = true;
        for (int j = t + 1; j < B; ++j)
            if (sidx[j] == sidx[t]) { win = false; break; }
        if (win) {
            int p = atomicAdd(&cnt, 1);
            int r = sidx[t];
            w_row[p] = r;
            w_lab[p] = labels[r];
            w_b[p] = t;
        }
        __syncthreads();
        if (t == 0) *nw = cnt;
    } else {
        // ---- private label histogram: block i owns hb row i ----
        __shared__ int lh[C];
        for (int i = t; i < C; i += 256) lh[i] = 0;
        __syncthreads();
        const int hb_i = blk - HIST_LO;
        const int stride = HIST_BLOCKS * 256;
        for (int i = hb_i * 256 + t; i < N; i += stride)
            atomicAdd(&lh[labels[i]], 1);
        __syncthreads();
        for (int i = t; i < C; i += 256) hb[hb_i * C + i] = lh[i];
    }
}

// K2: blk 0 = reduce hb -> cnts + exclusive scan -> offs/fillpos;
//     blks 1..256 = patch winner rows into out_feats (independent of scan).
__global__ __launch_bounds__(256) void k2_kernel(
    const float* __restrict__ new_rows, float* __restrict__ out_feats,
    const int* __restrict__ hb, int* __restrict__ offs, int* __restrict__ fillpos,
    int* __restrict__ cnts, const int* __restrict__ nw,
    const int* __restrict__ w_row, const int* __restrict__ w_b)
{
    const int blk = blockIdx.x;
    const int t = threadIdx.x;

    if (blk == 0) {
        __shared__ int swt[4];
        int base = t * 4;
        int h0 = 0, h1 = 0, h2 = 0, h3 = 0;
        for (int i = 0; i < HIST_BLOCKS; ++i) {
            const int* row = hb + i * C;
            if (base + 0 < C) h0 += row[base + 0];
            if (base + 1 < C) h1 += row[base + 1];
            if (base + 2 < C) h2 += row[base + 2];
            if (base + 3 < C) h3 += row[base + 3];
        }
        int tot = h0 + h1 + h2 + h3;
        int lane = t & 63;
        int scan = tot;
        #pragma unroll
        for (int off = 1; off < 64; off <<= 1) {
            int v = __shfl_up(scan, off);
            if (lane >= off) scan += v;
        }
        if (lane == 63) swt[t >> 6] = scan;
        __syncthreads();
        int wbase = 0;
        for (int i = 0; i < (t >> 6); ++i) wbase += swt[i];
        int excl = wbase + scan - tot;
        if (base + 0 < C) { offs[base + 0] = excl;                fillpos[base + 0] = excl;                cnts[base + 0] = h0; }
        if (base + 1 < C) { offs[base + 1] = excl + h0;           fillpos[base + 1] = excl + h0;           cnts[base + 1] = h1; }
        if (base + 2 < C) { offs[base + 2] = excl + h0 + h1;      fillpos[base + 2] = excl + h0 + h1;      cnts[base + 2] = h2; }
        if (base + 3 < C) { offs[base + 3] = excl + h0 + h1 + h2; fillpos[base + 3] = excl + h0 + h1 + h2; cnts[base + 3] = h3; }
    } else {
        int q = blk - 1;
        if (q < *nw)
            out_feats[(size_t)w_row[q] * D + t] = new_rows[w_b[q] * D + t];
    }
}

// K3: scatter row ids of touched clusters into contiguous per-cluster lists.
__global__ __launch_bounds__(256) void fill_kernel(
    const int* __restrict__ labels, const int* __restrict__ touched,
    int* __restrict__ fillpos, int* __restrict__ rowlist)
{
    int i = blockIdx.x * 256 + threadIdx.x;
    if (i >= N) return;
    int lab = labels[i];
    if (touched[lab]) {
        int p = atomicAdd(&fillpos[lab], 1);
        rowlist[p] = i;
    }
}

// K4: cluster mean from features (L3-hot) + winner correction; never reads
// out_feats (keeps it write-only => features stays MALL-resident).
//   sum = sum_{r in c} features[r] + sum_{w: lab_w==c}(new_rows[w_b]-features[w_row])
__global__ __launch_bounds__(1024) void cm_kernel(
    const float* __restrict__ cluster_mean, const float* __restrict__ features,
    const float* __restrict__ new_rows, const int* __restrict__ touched,
    const int* __restrict__ cnts, const int* __restrict__ offs,
    const int* __restrict__ rowlist, const int* __restrict__ nw,
    const int* __restrict__ w_row, const int* __restrict__ w_lab,
    const int* __restrict__ w_b, float* __restrict__ out_cm)
{
    const int c = blockIdx.x;
    const int d = threadIdx.x & 255;
    const int k = threadIdx.x >> 8;     // 0..3
    if (!touched[c]) {                  // block-uniform branch
        if (k == 0) out_cm[(size_t)c * D + d] = cluster_mean[(size_t)c * D + d];
        return;
    }
    __shared__ float red[3][256];
    const int cnt = cnts[c];
    const int off = offs[c];
    float acc = 0.0f;
    #pragma unroll 4
    for (int j = k; j < cnt; j += 4)
        acc += features[(size_t)rowlist[off + j] * D + d];
    const int nwv = *nw;
    for (int j = k; j < nwv; j += 4) {
        if (w_lab[j] == c)
            acc += new_rows[w_b[j] * D + d] - features[(size_t)w_row[j] * D + d];
    }
    if (k > 0) red[k - 1][d] = acc;
    __syncthreads();
    if (k == 0) {
        float tot = acc + red[0][d] + red[1][d] + red[2][d];
        out_cm[(size_t)c * D + d] = tot / fmaxf((float)cnt, 1.0f);
    }
}

extern "C" void kernel_launch(void* const* d_in, const int* in_sizes, int n_in,
                              void* d_out, int out_size, void* d_ws, size_t ws_size,
                              hipStream_t stream) {
    const float* inputs       = (const float*)d_in[0];
    const float* features     = (const float*)d_in[1];
    const float* cluster_mean = (const float*)d_in[2];
    const int*   indexes      = (const int*)d_in[3];
    const int*   labels       = (const int*)d_in[4];
    const int*   targets      = (const int*)d_in[5];

    float* out_logits = (float*)d_out;                      // B*C
    float* out_feats  = out_logits + (size_t)B * C;         // N*D
    float* out_cm     = out_feats + (size_t)N * D;          // C*D

    char* ws = (char*)d_ws;
    float* new_rows = (float*)(ws + WS_NEWROWS_OFF);
    int*   nw       = (int*)(ws + WS_NW_OFF);
    int*   offs     = (int*)(ws + WS_OFFS_OFF);
    int*   fillpos  = (int*)(ws + WS_FILLPOS_OFF);
    int*   cnts     = (int*)(ws + WS_CNTS_OFF);
    int*   touched  = (int*)(ws + WS_TOUCHED_OFF);
    int*   w_row    = (int*)(ws + WS_WROW_OFF);
    int*   w_lab    = (int*)(ws + WS_WLAB_OFF);
    int*   w_b      = (int*)(ws + WS_WB_OFF);
    int*   hb       = (int*)(ws + WS_HB_OFF);
    int*   rowlist  = (int*)(ws + WS_ROWLIST_OFF);

    k1_kernel<<<K1_BLOCKS, 256, 0, stream>>>(inputs, features, cluster_mean,
                                             indexes, labels, targets,
                                             out_logits, out_feats, new_rows,
                                             hb, touched, nw, w_row, w_lab, w_b);
    k2_kernel<<<257, 256, 0, stream>>>(new_rows, out_feats, hb, offs, fillpos,
                                       cnts, nw, w_row, w_b);
    fill_kernel<<<(N + 255) / 256, 256, 0, stream>>>(labels, touched, fillpos, rowlist);
    cm_kernel<<<C, 1024, 0, stream>>>(cluster_mean, features, new_rows, touched,
                                      cnts, offs, rowlist, nw, w_row, w_lab, w_b,
                                      out_cm);
}

// Round 14
// 151.391 us; speedup vs baseline: 2.2175x; 1.0972x over previous
//
#include <hip/hip_runtime.h>

typedef float f32x4 __attribute__((ext_vector_type(4)));

#define B 256
#define D 256
#define N 200000
#define C 1000

// ---- K1 block map (R9-exact geometry: side work first, copy LAST) ----
#define K1_BLOCKS   2048
#define LOGITS_LO   0      // 256 blocks: logits
#define NEWROWS_LO  256    // 256 blocks: new_rows
#define WIN_BLK     512    // 1 block: touched + winner resolve
#define HIST_LO     513    // 64 blocks: private histograms (no atomics, no zero)
#define HIST_BLOCKS 64
#define COPY_LO     577    // 1471 blocks: NT-store bulk copy
#define COPY_BLOCKS (K1_BLOCKS - COPY_LO)

// ---------------- ws layout (bytes) ----------------
#define WS_NEWROWS_OFF  0          // B*D f32 = 262144
#define WS_NW_OFF       262144     // 1 int
#define WS_OFFS_OFF     262148     // C int
#define WS_FILLPOS_OFF  266148     // C int
#define WS_CNTS_OFF     270148     // C int
#define WS_TOUCHED_OFF  274148     // C int
#define WS_WROW_OFF     278148     // B int
#define WS_WLAB_OFF     279172     // B int
#define WS_WB_OFF       280196     // B int
#define WS_HB_OFF       281220     // 64*C int = 256000
#define WS_ROWLIST_OFF  537220     // N int = 800000 -> total 1,337,220

// K1: logits (0..255) || new_rows (256..511) || touched+winners (512)
//     || private label hists (513..576) || NT-store copy (577..2047).
// Copy: cached loads (features stays MALL-resident across graph replays) + NT
// stores (writes don't evict it). R9-measured best: timed ~98 us warm.
// Copy-first block order (R13) regressed 15% — keep copy LAST.
__global__ __launch_bounds__(256) void k1_kernel(
    const float* __restrict__ inputs, const float* __restrict__ features,
    const float* __restrict__ cluster_mean, const int* __restrict__ indexes,
    const int* __restrict__ labels, const int* __restrict__ targets,
    float* __restrict__ out_logits, float* __restrict__ out_feats,
    float* __restrict__ new_rows, int* __restrict__ hb, int* __restrict__ touched,
    int* __restrict__ nw, int* __restrict__ w_row, int* __restrict__ w_lab,
    int* __restrict__ w_b)
{
    const int blk = blockIdx.x;
    const int t = threadIdx.x;

    if (blk >= COPY_LO) {
        const f32x4* src = (const f32x4*)features;
        f32x4*       dst = (f32x4*)out_feats;
        const int total4 = N * (D / 4);            // 12,800,000
        const int stride = COPY_BLOCKS * 256;      // 376,576
        int i = (blk - COPY_LO) * 256 + t;
        for (; i + 3 * stride < total4; i += 4 * stride) {
            f32x4 v0 = src[i];
            f32x4 v1 = src[i + stride];
            f32x4 v2 = src[i + 2 * stride];
            f32x4 v3 = src[i + 3 * stride];
            __builtin_nontemporal_store(v0, dst + i);
            __builtin_nontemporal_store(v1, dst + i + stride);
            __builtin_nontemporal_store(v2, dst + i + 2 * stride);
            __builtin_nontemporal_store(v3, dst + i + 3 * stride);
        }
        for (; i < total4; i += stride)
            __builtin_nontemporal_store(src[i], dst + i);
    } else if (blk < NEWROWS_LO) {
        // ---- logits[b,:] = inputs[b] @ cluster_mean.T ----
        __shared__ float sbuf[D];
        int b = blk - LOGITS_LO;
        sbuf[t] = inputs[b * D + t];
        __syncthreads();
        const f32x4* cmv = (const f32x4*)cluster_mean;
        for (int c = t; c < C; c += 256) {
            const f32x4* cm = cmv + (size_t)c * 64;
            float a0 = 0.f, a1 = 0.f, a2 = 0.f, a3 = 0.f;
            #pragma unroll 8
            for (int d4 = 0; d4 < 64; ++d4) {
                f32x4 v = cm[d4];
                const float* si = sbuf + d4 * 4;
                a0 += v.x * si[0];
                a1 += v.y * si[1];
                a2 += v.z * si[2];
                a3 += v.w * si[3];
            }
            out_logits[(size_t)b * C + c] = (a0 + a1) + (a2 + a3);
        }
    } else if (blk < WIN_BLK) {
        // ---- new_rows[b] = l2norm(0.5*features[indexes[b]] + 0.5*inputs[b]) ----
        __shared__ float wpart[4];
        __shared__ float stot;
        int b = blk - NEWROWS_LO;
        int r = indexes[b];
        float x = 0.5f * features[(size_t)r * D + t] + 0.5f * inputs[b * D + t];
        float s = x * x;
        #pragma unroll
        for (int off = 32; off > 0; off >>= 1) s += __shfl_down(s, off);
        if ((t & 63) == 0) wpart[t >> 6] = s;
        __syncthreads();
        if (t == 0) stot = (wpart[0] + wpart[1]) + (wpart[2] + wpart[3]);
        __syncthreads();
        new_rows[b * D + t] = x / sqrtf(stot + 1e-12f);
    } else if (blk == WIN_BLK) {
        // ---- zero+mark touched; resolve last-write-wins winners ----
        __shared__ int sidx[B];
        __shared__ int cnt;
        for (int i = t; i < C; i += 256) touched[i] = 0;
        sidx[t] = indexes[t];
        if (t == 0) cnt = 0;
        __syncthreads();
        touched[targets[t]] = 1;
        bool win = true;
        for (int j = t + 1; j < B; ++j)
            if (sidx[j] == sidx[t]) { win = false; break; }
        if (win) {
            int p = atomicAdd(&cnt, 1);
            int r = sidx[t];
            w_row[p] = r;
            w_lab[p] = labels[r];
            w_b[p] = t;
        }
        __syncthreads();
        if (t == 0) *nw = cnt;
    } else {
        // ---- private label histogram: block i owns hb row i ----
        __shared__ int lh[C];
        for (int i = t; i < C; i += 256) lh[i] = 0;
        __syncthreads();
        const int hb_i = blk - HIST_LO;
        const int stride = HIST_BLOCKS * 256;
        for (int i = hb_i * 256 + t; i < N; i += stride)
            atomicAdd(&lh[labels[i]], 1);
        __syncthreads();
        for (int i = t; i < C; i += 256) hb[hb_i * C + i] = lh[i];
    }
}

// K2: blk 0 = reduce hb -> cnts + exclusive scan -> offs/fillpos;
//     blks 1..256 = patch winner rows into out_feats (independent of scan).
__global__ __launch_bounds__(256) void k2_kernel(
    const float* __restrict__ new_rows, float* __restrict__ out_feats,
    const int* __restrict__ hb, int* __restrict__ offs, int* __restrict__ fillpos,
    int* __restrict__ cnts, const int* __restrict__ nw,
    const int* __restrict__ w_row, const int* __restrict__ w_b)
{
    const int blk = blockIdx.x;
    const int t = threadIdx.x;

    if (blk == 0) {
        __shared__ int swt[4];
        int base = t * 4;
        int h0 = 0, h1 = 0, h2 = 0, h3 = 0;
        for (int i = 0; i < HIST_BLOCKS; ++i) {
            const int* row = hb + i * C;
            if (base + 0 < C) h0 += row[base + 0];
            if (base + 1 < C) h1 += row[base + 1];
            if (base + 2 < C) h2 += row[base + 2];
            if (base + 3 < C) h3 += row[base + 3];
        }
        int tot = h0 + h1 + h2 + h3;
        int lane = t & 63;
        int scan = tot;
        #pragma unroll
        for (int off = 1; off < 64; off <<= 1) {
            int v = __shfl_up(scan, off);
            if (lane >= off) scan += v;
        }
        if (lane == 63) swt[t >> 6] = scan;
        __syncthreads();
        int wbase = 0;
        for (int i = 0; i < (t >> 6); ++i) wbase += swt[i];
        int excl = wbase + scan - tot;
        if (base + 0 < C) { offs[base + 0] = excl;                fillpos[base + 0] = excl;                cnts[base + 0] = h0; }
        if (base + 1 < C) { offs[base + 1] = excl + h0;           fillpos[base + 1] = excl + h0;           cnts[base + 1] = h1; }
        if (base + 2 < C) { offs[base + 2] = excl + h0 + h1;      fillpos[base + 2] = excl + h0 + h1;      cnts[base + 2] = h2; }
        if (base + 3 < C) { offs[base + 3] = excl + h0 + h1 + h2; fillpos[base + 3] = excl + h0 + h1 + h2; cnts[base + 3] = h3; }
    } else {
        int q = blk - 1;
        if (q < *nw)
            out_feats[(size_t)w_row[q] * D + t] = new_rows[w_b[q] * D + t];
    }
}

// K3: scatter row ids of touched clusters into contiguous per-cluster lists.
__global__ __launch_bounds__(256) void fill_kernel(
    const int* __restrict__ labels, const int* __restrict__ touched,
    int* __restrict__ fillpos, int* __restrict__ rowlist)
{
    int i = blockIdx.x * 256 + threadIdx.x;
    if (i >= N) return;
    int lab = labels[i];
    if (touched[lab]) {
        int p = atomicAdd(&fillpos[lab], 1);
        rowlist[p] = i;
    }
}

// K4: cluster mean from features (L3-hot) + winner correction; never reads
// out_feats (keeps it write-only => features stays MALL-resident).
//   sum = sum_{r in c} features[r] + sum_{w: lab_w==c}(new_rows[w_b]-features[w_row])
__global__ __launch_bounds__(1024) void cm_kernel(
    const float* __restrict__ cluster_mean, const float* __restrict__ features,
    const float* __restrict__ new_rows, const int* __restrict__ touched,
    const int* __restrict__ cnts, const int* __restrict__ offs,
    const int* __restrict__ rowlist, const int* __restrict__ nw,
    const int* __restrict__ w_row, const int* __restrict__ w_lab,
    const int* __restrict__ w_b, float* __restrict__ out_cm)
{
    const int c = blockIdx.x;
    const int d = threadIdx.x & 255;
    const int k = threadIdx.x >> 8;     // 0..3
    if (!touched[c]) {                  // block-uniform branch
        if (k == 0) out_cm[(size_t)c * D + d] = cluster_mean[(size_t)c * D + d];
        return;
    }
    __shared__ float red[3][256];
    const int cnt = cnts[c];
    const int off = offs[c];
    float acc = 0.0f;
    #pragma unroll 4
    for (int j = k; j < cnt; j += 4)
        acc += features[(size_t)rowlist[off + j] * D + d];
    const int nwv = *nw;
    for (int j = k; j < nwv; j += 4) {
        if (w_lab[j] == c)
            acc += new_rows[w_b[j] * D + d] - features[(size_t)w_row[j] * D + d];
    }
    if (k > 0) red[k - 1][d] = acc;
    __syncthreads();
    if (k == 0) {
        float tot = acc + red[0][d] + red[1][d] + red[2][d];
        out_cm[(size_t)c * D + d] = tot / fmaxf((float)cnt, 1.0f);
    }
}

extern "C" void kernel_launch(void* const* d_in, const int* in_sizes, int n_in,
                              void* d_out, int out_size, void* d_ws, size_t ws_size,
                              hipStream_t stream) {
    const float* inputs       = (const float*)d_in[0];
    const float* features     = (const float*)d_in[1];
    const float* cluster_mean = (const float*)d_in[2];
    const int*   indexes      = (const int*)d_in[3];
    const int*   labels       = (const int*)d_in[4];
    const int*   targets      = (const int*)d_in[5];

    float* out_logits = (float*)d_out;                      // B*C
    float* out_feats  = out_logits + (size_t)B * C;         // N*D
    float* out_cm     = out_feats + (size_t)N * D;          // C*D

    char* ws = (char*)d_ws;
    float* new_rows = (float*)(ws + WS_NEWROWS_OFF);
    int*   nw       = (int*)(ws + WS_NW_OFF);
    int*   offs     = (int*)(ws + WS_OFFS_OFF);
    int*   fillpos  = (int*)(ws + WS_FILLPOS_OFF);
    int*   cnts     = (int*)(ws + WS_CNTS_OFF);
    int*   touched  = (int*)(ws + WS_TOUCHED_OFF);
    int*   w_row    = (int*)(ws + WS_WROW_OFF);
    int*   w_lab    = (int*)(ws + WS_WLAB_OFF);
    int*   w_b      = (int*)(ws + WS_WB_OFF);
    int*   hb       = (int*)(ws + WS_HB_OFF);
    int*   rowlist  = (int*)(ws + WS_ROWLIST_OFF);

    k1_kernel<<<K1_BLOCKS, 256, 0, stream>>>(inputs, features, cluster_mean,
                                             indexes, labels, targets,
                                             out_logits, out_feats, new_rows,
                                             hb, touched, nw, w_row, w_lab, w_b);
    k2_kernel<<<257, 256, 0, stream>>>(new_rows, out_feats, hb, offs, fillpos,
                                       cnts, nw, w_row, w_b);
    fill_kernel<<<(N + 255) / 256, 256, 0, stream>>>(labels, touched, fillpos, rowlist);
    cm_kernel<<<C, 1024, 0, stream>>>(cluster_mean, features, new_rows, touched,
                                      cnts, offs, rowlist, nw, w_row, w_lab, w_b,
                                      out_cm);
}

// Round 15
// 123.278 us; speedup vs baseline: 2.7232x; 1.2280x over previous
//
#include <hip/hip_runtime.h>

typedef float f32x4 __attribute__((ext_vector_type(4)));

#define B 256
#define D 256
#define N 200000
#define C 1000

// ---- K1 block map (R9-exact geometry: side work first, copy LAST) ----
#define K1_BLOCKS   2048
#define LOGITS_LO   0      // 256 blocks: logits
#define NEWROWS_LO  256    // 256 blocks: new_rows
#define WIN_BLK     512    // 1 block: touched + winner resolve
#define HIST_LO     513    // 64 blocks: LDS-private hist + atomic merge
#define HIST_BLOCKS 64
#define COPY_LO     577    // 1471 blocks: NT-store bulk copy
#define COPY_BLOCKS (K1_BLOCKS - COPY_LO)

// ---------------- ws layout (bytes) ----------------
#define WS_NEWROWS_OFF  0          // B*D f32 = 262144
#define WS_NW_OFF       262144     // 1 int
#define WS_OFFS_OFF     262148     // C int
#define WS_FILLPOS_OFF  266148     // C int
#define WS_HIST_OFF     270148     // C int (zeroed by k0)
#define WS_TOUCHED_OFF  274148     // C int (zeroed by WIN_BLK)
#define WS_WROW_OFF     278148     // B int
#define WS_WLAB_OFF     279172     // B int
#define WS_WB_OFF       280196     // B int
#define WS_ROWLIST_OFF  281220     // N int = 800000 -> total 1,081,220

// K0: zero hist (1000 ints). Must precede K1's atomic merge.
__global__ __launch_bounds__(256) void k0_zero(int* __restrict__ hist) {
    int i = blockIdx.x * 256 + threadIdx.x;
    if (i < C) hist[i] = 0;
}

// K1: logits (0..255) || new_rows (256..511) || touched+winners (512)
//     || label hist via LDS + atomic merge (513..576) || NT-store copy (577..2047).
// Copy: cached loads (features stays MALL-resident across graph replays) + NT
// stores (writes don't evict it). Timed-warm ~98 us (R9). Copy must stay LAST
// (R13: copy-first regressed 15%). Hist merge must stay in K1's shadow
// (R14: moving the 64-partial reduce to k2's scan block cost ~20 us serial).
__global__ __launch_bounds__(256) void k1_kernel(
    const float* __restrict__ inputs, const float* __restrict__ features,
    const float* __restrict__ cluster_mean, const int* __restrict__ indexes,
    const int* __restrict__ labels, const int* __restrict__ targets,
    float* __restrict__ out_logits, float* __restrict__ out_feats,
    float* __restrict__ new_rows, int* __restrict__ hist, int* __restrict__ touched,
    int* __restrict__ nw, int* __restrict__ w_row, int* __restrict__ w_lab,
    int* __restrict__ w_b)
{
    const int blk = blockIdx.x;
    const int t = threadIdx.x;

    if (blk >= COPY_LO) {
        const f32x4* src = (const f32x4*)features;
        f32x4*       dst = (f32x4*)out_feats;
        const int total4 = N * (D / 4);            // 12,800,000
        const int stride = COPY_BLOCKS * 256;      // 376,576
        int i = (blk - COPY_LO) * 256 + t;
        for (; i + 3 * stride < total4; i += 4 * stride) {
            f32x4 v0 = src[i];
            f32x4 v1 = src[i + stride];
            f32x4 v2 = src[i + 2 * stride];
            f32x4 v3 = src[i + 3 * stride];
            __builtin_nontemporal_store(v0, dst + i);
            __builtin_nontemporal_store(v1, dst + i + stride);
            __builtin_nontemporal_store(v2, dst + i + 2 * stride);
            __builtin_nontemporal_store(v3, dst + i + 3 * stride);
        }
        for (; i < total4; i += stride)
            __builtin_nontemporal_store(src[i], dst + i);
    } else if (blk < NEWROWS_LO) {
        // ---- logits[b,:] = inputs[b] @ cluster_mean.T ----
        __shared__ float sbuf[D];
        int b = blk - LOGITS_LO;
        sbuf[t] = inputs[b * D + t];
        __syncthreads();
        const f32x4* cmv = (const f32x4*)cluster_mean;
        for (int c = t; c < C; c += 256) {
            const f32x4* cm = cmv + (size_t)c * 64;
            float a0 = 0.f, a1 = 0.f, a2 = 0.f, a3 = 0.f;
            #pragma unroll 8
            for (int d4 = 0; d4 < 64; ++d4) {
                f32x4 v = cm[d4];
                const float* si = sbuf + d4 * 4;
                a0 += v.x * si[0];
                a1 += v.y * si[1];
                a2 += v.z * si[2];
                a3 += v.w * si[3];
            }
            out_logits[(size_t)b * C + c] = (a0 + a1) + (a2 + a3);
        }
    } else if (blk < WIN_BLK) {
        // ---- new_rows[b] = l2norm(0.5*features[indexes[b]] + 0.5*inputs[b]) ----
        __shared__ float wpart[4];
        __shared__ float stot;
        int b = blk - NEWROWS_LO;
        int r = indexes[b];
        float x = 0.5f * features[(size_t)r * D + t] + 0.5f * inputs[b * D + t];
        float s = x * x;
        #pragma unroll
        for (int off = 32; off > 0; off >>= 1) s += __shfl_down(s, off);
        if ((t & 63) == 0) wpart[t >> 6] = s;
        __syncthreads();
        if (t == 0) stot = (wpart[0] + wpart[1]) + (wpart[2] + wpart[3]);
        __syncthreads();
        new_rows[b * D + t] = x / sqrtf(stot + 1e-12f);
    } else if (blk == WIN_BLK) {
        // ---- zero+mark touched; resolve last-write-wins winners ----
        __shared__ int sidx[B];
        __shared__ int cnt;
        for (int i = t; i < C; i += 256) touched[i] = 0;
        sidx[t] = indexes[t];
        if (t == 0) cnt = 0;
        __syncthreads();
        touched[targets[t]] = 1;
        bool win = true;
        for (int j = t + 1; j < B; ++j)
            if (sidx[j] == sidx[t]) { win = false; break; }
        if (win) {
            int p = atomicAdd(&cnt, 1);
            int r = sidx[t];
            w_row[p] = r;
            w_lab[p] = labels[r];
            w_b[p] = t;
        }
        __syncthreads();
        if (t == 0) *nw = cnt;
    } else {
        // ---- label histogram: LDS-private, then atomic merge (copy's shadow) ----
        __shared__ int lh[C];
        for (int i = t; i < C; i += 256) lh[i] = 0;
        __syncthreads();
        const int stride = HIST_BLOCKS * 256;
        for (int i = (blk - HIST_LO) * 256 + t; i < N; i += stride)
            atomicAdd(&lh[labels[i]], 1);
        __syncthreads();
        for (int i = t; i < C; i += 256) {
            int v = lh[i];
            if (v) atomicAdd(&hist[i], v);
        }
    }
}

// K2: blk 0 = exclusive scan of hist -> offs/fillpos (hist already reduced);
//     blks 1..256 = patch winner rows into out_feats.
__global__ __launch_bounds__(256) void k2_kernel(
    const float* __restrict__ new_rows, float* __restrict__ out_feats,
    const int* __restrict__ hist, int* __restrict__ offs, int* __restrict__ fillpos,
    const int* __restrict__ nw, const int* __restrict__ w_row,
    const int* __restrict__ w_b)
{
    const int blk = blockIdx.x;
    const int t = threadIdx.x;

    if (blk == 0) {
        __shared__ int swt[4];
        int base = t * 4;
        int h0 = (base + 0 < C) ? hist[base + 0] : 0;
        int h1 = (base + 1 < C) ? hist[base + 1] : 0;
        int h2 = (base + 2 < C) ? hist[base + 2] : 0;
        int h3 = (base + 3 < C) ? hist[base + 3] : 0;
        int tot = h0 + h1 + h2 + h3;
        int lane = t & 63;
        int scan = tot;
        #pragma unroll
        for (int off = 1; off < 64; off <<= 1) {
            int v = __shfl_up(scan, off);
            if (lane >= off) scan += v;
        }
        if (lane == 63) swt[t >> 6] = scan;
        __syncthreads();
        int wbase = 0;
        for (int i = 0; i < (t >> 6); ++i) wbase += swt[i];
        int excl = wbase + scan - tot;
        if (base + 0 < C) { offs[base + 0] = excl;                fillpos[base + 0] = excl; }
        if (base + 1 < C) { offs[base + 1] = excl + h0;           fillpos[base + 1] = excl + h0; }
        if (base + 2 < C) { offs[base + 2] = excl + h0 + h1;      fillpos[base + 2] = excl + h0 + h1; }
        if (base + 3 < C) { offs[base + 3] = excl + h0 + h1 + h2; fillpos[base + 3] = excl + h0 + h1 + h2; }
    } else {
        int q = blk - 1;
        if (q < *nw)
            out_feats[(size_t)w_row[q] * D + t] = new_rows[w_b[q] * D + t];
    }
}

// K3: scatter row ids of touched clusters into contiguous per-cluster lists.
__global__ __launch_bounds__(256) void fill_kernel(
    const int* __restrict__ labels, const int* __restrict__ touched,
    int* __restrict__ fillpos, int* __restrict__ rowlist)
{
    int i = blockIdx.x * 256 + threadIdx.x;
    if (i >= N) return;
    int lab = labels[i];
    if (touched[lab]) {
        int p = atomicAdd(&fillpos[lab], 1);
        rowlist[p] = i;
    }
}

// K4: cluster mean from features (L3-hot) + winner correction; never reads
// out_feats (keeps it write-only => features stays MALL-resident).
//   sum = sum_{r in c} features[r] + sum_{w: lab_w==c}(new_rows[w_b]-features[w_row])
__global__ __launch_bounds__(1024) void cm_kernel(
    const float* __restrict__ cluster_mean, const float* __restrict__ features,
    const float* __restrict__ new_rows, const int* __restrict__ touched,
    const int* __restrict__ hist, const int* __restrict__ offs,
    const int* __restrict__ rowlist, const int* __restrict__ nw,
    const int* __restrict__ w_row, const int* __restrict__ w_lab,
    const int* __restrict__ w_b, float* __restrict__ out_cm)
{
    const int c = blockIdx.x;
    const int d = threadIdx.x & 255;
    const int k = threadIdx.x >> 8;     // 0..3
    if (!touched[c]) {                  // block-uniform branch
        if (k == 0) out_cm[(size_t)c * D + d] = cluster_mean[(size_t)c * D + d];
        return;
    }
    __shared__ float red[3][256];
    const int cnt = hist[c];
    const int off = offs[c];
    float acc = 0.0f;
    #pragma unroll 4
    for (int j = k; j < cnt; j += 4)
        acc += features[(size_t)rowlist[off + j] * D + d];
    const int nwv = *nw;
    for (int j = k; j < nwv; j += 4) {
        if (w_lab[j] == c)
            acc += new_rows[w_b[j] * D + d] - features[(size_t)w_row[j] * D + d];
    }
    if (k > 0) red[k - 1][d] = acc;
    __syncthreads();
    if (k == 0) {
        float tot = acc + red[0][d] + red[1][d] + red[2][d];
        out_cm[(size_t)c * D + d] = tot / fmaxf((float)cnt, 1.0f);
    }
}

extern "C" void kernel_launch(void* const* d_in, const int* in_sizes, int n_in,
                              void* d_out, int out_size, void* d_ws, size_t ws_size,
                              hipStream_t stream) {
    const float* inputs       = (const float*)d_in[0];
    const float* features     = (const float*)d_in[1];
    const float* cluster_mean = (const float*)d_in[2];
    const int*   indexes      = (const int*)d_in[3];
    const int*   labels       = (const int*)d_in[4];
    const int*   targets      = (const int*)d_in[5];

    float* out_logits = (float*)d_out;                      // B*C
    float* out_feats  = out_logits + (size_t)B * C;         // N*D
    float* out_cm     = out_feats + (size_t)N * D;          // C*D

    char* ws = (char*)d_ws;
    float* new_rows = (float*)(ws + WS_NEWROWS_OFF);
    int*   nw       = (int*)(ws + WS_NW_OFF);
    int*   offs     = (int*)(ws + WS_OFFS_OFF);
    int*   fillpos  = (int*)(ws + WS_FILLPOS_OFF);
    int*   hist     = (int*)(ws + WS_HIST_OFF);
    int*   touched  = (int*)(ws + WS_TOUCHED_OFF);
    int*   w_row    = (int*)(ws + WS_WROW_OFF);
    int*   w_lab    = (int*)(ws + WS_WLAB_OFF);
    int*   w_b      = (int*)(ws + WS_WB_OFF);
    int*   rowlist  = (int*)(ws + WS_ROWLIST_OFF);

    k0_zero<<<(C + 255) / 256, 256, 0, stream>>>(hist);
    k1_kernel<<<K1_BLOCKS, 256, 0, stream>>>(inputs, features, cluster_mean,
                                             indexes, labels, targets,
                                             out_logits, out_feats, new_rows,
                                             hist, touched, nw, w_row, w_lab, w_b);
    k2_kernel<<<257, 256, 0, stream>>>(new_rows, out_feats, hist, offs, fillpos,
                                       nw, w_row, w_b);
    fill_kernel<<<(N + 255) / 256, 256, 0, stream>>>(labels, touched, fillpos, rowlist);
    cm_kernel<<<C, 1024, 0, stream>>>(cluster_mean, features, new_rows, touched,
                                      hist, offs, rowlist, nw, w_row, w_lab, w_b,
                                      out_cm);
}